// Round 4
// baseline (772.654 us; speedup 1.0000x reference)
//
#include <hip/hip_runtime.h>
#include <math.h>

#define N_NODES 50000
#define N_EDGES 800000
#define DIM_IN 64
#define DIM_HID 128
#define DIM_OUT 64
#define PAD 136   // bf16 per weight row: 272B, 16B-aligned

typedef __attribute__((ext_vector_type(8))) short short8;   // 8 bf16 (4 VGPRs)
typedef __attribute__((ext_vector_type(4))) float f32x4;    // MFMA accumulator

union U8 { uint4 u; short8 s; };

// RTNE float->bf16 (inputs finite)
__device__ __forceinline__ unsigned short f2bf(float f) {
    unsigned u = __float_as_uint(f);
    return (unsigned short)((u + 0x7fffu + ((u >> 16) & 1u)) >> 16);
}

__device__ __forceinline__ unsigned cvt_pk_bf16(float a, float b) {
#if __has_builtin(__builtin_amdgcn_cvt_pk_bf16_f32)
    auto pk = __builtin_amdgcn_cvt_pk_bf16_f32(a, b);   // lo=a, hi=b
    unsigned d; __builtin_memcpy(&d, &pk, 4);
    return d;
#else
    return (unsigned)f2bf(a) | ((unsigned)f2bf(b) << 16);
#endif
}

__device__ __forceinline__ float exp2_fast(float a) {
#if __has_builtin(__builtin_amdgcn_exp2f)
    return __builtin_amdgcn_exp2f(a);
#else
    return __expf(a * 0.69314718f);
#endif
}

// softplus(x) = max(x,0) + log1p(exp(-|x|)); log1p(z) ~ z*(1 + z*(-0.5 + z*(A + z*B)))
// cubic fit on z in (0,1], max abs err ~1.5e-3 (below bf16 quantization of H)
__device__ __forceinline__ unsigned sp2(float x0, float x1) {
    const float L2E = 1.44269504f;
    float z0 = exp2_fast(-fabsf(x0) * L2E);
    float z1 = exp2_fast(-fabsf(x1) * L2E);
    float p0 = fmaf(fmaf(fmaf(-0.1011458f, z0, 0.2942925f), z0, -0.5f), z0, 1.0f) * z0;
    float p1 = fmaf(fmaf(fmaf(-0.1011458f, z1, 0.2942925f), z1, -0.5f), z1, 1.0f) * z1;
    return cvt_pk_bf16(fmaxf(x0, 0.0f) + p0, fmaxf(x1, 0.0f) + p1);
}

// Weights -> bf16 W^T [n][PAD] (k-contiguous). Layers 1,2 get the K-permutation
// pi(s) matching the MFMA C-layout->B-frag register renaming (see kernel).
__global__ void prep_weights(const float* __restrict__ W0,
                             const float* __restrict__ W1,
                             const float* __restrict__ W2,
                             unsigned short* __restrict__ wt) {
    int i = blockIdx.x * blockDim.x + threadIdx.x;
    if (i >= 320 * PAD) return;
    int row = i / PAD, s = i - row * PAD;
    float v = 0.f;
    if (s < 128) {
        int f = ((s >> 5) << 5) | (((s & 7) >> 2) << 4) | (((s >> 3) & 3) << 2) | (s & 3);
        if (row < 128)      v = W0[s * DIM_HID + row];          // layer 0: natural k
        else if (row < 256) v = W1[f * DIM_HID + (row - 128)];  // layer 1: permuted k
        else                v = W2[f * DIM_OUT + (row - 256)];  // layer 2: permuted k
    }
    wt[i] = f2bf(v);
}

// Flipped GEMM: each layer computes H^T = W^T * H_prev^T via
// mfma(A=weight-frag, B=activation-frag). C-layout: col=l16=edge, row=q*4+r=feature.
// A lane therefore keeps its own edges' activations; the layer->layer transform is
// softplus + cvt_pk + register renaming (K-permutation folded into the weights).
// No shared memory, no barriers, no shuffles.
__global__ __launch_bounds__(256, 4)
void edge_mlp_mfma(const float* __restrict__ x,
                   const int* __restrict__ eidx,
                   const unsigned short* __restrict__ wt,
                   const float* __restrict__ b0,
                   const float* __restrict__ b1,
                   const float* __restrict__ b2,
                   float* __restrict__ out) {
    const int lane = threadIdx.x & 63;
    const int w    = threadIdx.x >> 6;
    const int l16  = lane & 15;
    const int q    = lane >> 4;
    const int e0w  = blockIdx.x * 128 + w * 32;   // this wave's 32 edges

    const unsigned short* Wt0 = wt;
    const unsigned short* Wt1 = wt + 128 * PAD;
    const unsigned short* Wt2 = wt + 256 * PAD;

    int nodeR[2], nodeC[2];
#pragma unroll
    for (int m = 0; m < 2; ++m) {
        nodeR[m] = eidx[e0w + m * 16 + l16];
        nodeC[m] = eidx[N_EDGES + e0w + m * 16 + l16];
    }

    // layer-0 B-frags straight from x: B(k=kk*32+q*8+j, edge=m*16+l16)
    short8 hfr[2][4];
#pragma unroll
    for (int m = 0; m < 2; ++m)
#pragma unroll
        for (int kk = 0; kk < 4; ++kk) {
            int node = (kk >= 2) ? nodeC[m] : nodeR[m];
            const float* p = x + (size_t)node * DIM_IN + (kk & 1) * 32 + q * 8;
            float4 v0 = *(const float4*)p;
            float4 v1 = *(const float4*)(p + 4);
            U8 t;
            t.u.x = cvt_pk_bf16(v0.x, v0.y);
            t.u.y = cvt_pk_bf16(v0.z, v0.w);
            t.u.z = cvt_pk_bf16(v1.x, v1.y);
            t.u.w = cvt_pk_bf16(v1.z, v1.w);
            hfr[m][kk] = t.s;
        }

    // ---- layers 0,1: H^T = softplus(W^T H^T + b) ----
#pragma unroll
    for (int L = 0; L < 2; ++L) {
        const unsigned short* W = L ? Wt1 : Wt0;
        const float* bias = L ? b1 : b0;
        unsigned d[2][8][2];
#pragma unroll
        for (int ti = 0; ti < 8; ++ti) {
            f32x4 bb = *(const f32x4*)(bias + ti * 16 + q * 4);  // bias on row dim
            f32x4 a0 = bb, a1 = bb;
            const unsigned short* Wp = W + (ti * 16 + l16) * PAD + q * 8;
            short8 wf[4];
#pragma unroll
            for (int kk = 0; kk < 4; ++kk)
                wf[kk] = *(const short8*)(Wp + kk * 32);
#pragma unroll
            for (int kk = 0; kk < 4; ++kk) {
                a0 = __builtin_amdgcn_mfma_f32_16x16x32_bf16(wf[kk], hfr[0][kk], a0, 0, 0, 0);
                a1 = __builtin_amdgcn_mfma_f32_16x16x32_bf16(wf[kk], hfr[1][kk], a1, 0, 0, 0);
            }
            // per-ti epilogue keeps acc liveness at 8 VGPRs
            d[0][ti][0] = sp2(a0[0], a0[1]);
            d[0][ti][1] = sp2(a0[2], a0[3]);
            d[1][ti][0] = sp2(a1[0], a1[1]);
            d[1][ti][1] = sp2(a1[2], a1[3]);
        }
        // next-layer B-frags: pure register renaming (weights carry pi)
#pragma unroll
        for (int m = 0; m < 2; ++m)
#pragma unroll
            for (int kk = 0; kk < 4; ++kk) {
                U8 t;
                t.u.x = d[m][2 * kk][0];
                t.u.y = d[m][2 * kk][1];
                t.u.z = d[m][2 * kk + 1][0];
                t.u.w = d[m][2 * kk + 1][1];
                hfr[m][kk] = t.s;
            }
    }

    // ---- layer 2: O^T = W2^T H2^T + b2, scatter-add (node uniform per lane) ----
#pragma unroll
    for (int ti = 0; ti < 4; ++ti) {
        f32x4 bb = *(const f32x4*)(b2 + ti * 16 + q * 4);
        f32x4 a0 = bb, a1 = bb;
        const unsigned short* Wp = Wt2 + (ti * 16 + l16) * PAD + q * 8;
        short8 wf[4];
#pragma unroll
        for (int kk = 0; kk < 4; ++kk)
            wf[kk] = *(const short8*)(Wp + kk * 32);
#pragma unroll
        for (int kk = 0; kk < 4; ++kk) {
            a0 = __builtin_amdgcn_mfma_f32_16x16x32_bf16(wf[kk], hfr[0][kk], a0, 0, 0, 0);
            a1 = __builtin_amdgcn_mfma_f32_16x16x32_bf16(wf[kk], hfr[1][kk], a1, 0, 0, 0);
        }
        float* p0 = out + (size_t)nodeR[0] * DIM_OUT + ti * 16 + q * 4;
        float* p1 = out + (size_t)nodeR[1] * DIM_OUT + ti * 16 + q * 4;
#pragma unroll
        for (int r = 0; r < 4; ++r) {
            atomicAdd(p0 + r, a0[r]);
            atomicAdd(p1 + r, a1[r]);
        }
    }
}

extern "C" void kernel_launch(void* const* d_in, const int* in_sizes, int n_in,
                              void* d_out, int out_size, void* d_ws, size_t ws_size,
                              hipStream_t stream) {
    const float* x  = (const float*)d_in[0];
    const int*   ei = (const int*)d_in[1];
    const float* W0 = (const float*)d_in[2];
    const float* b0 = (const float*)d_in[3];
    const float* W1 = (const float*)d_in[4];
    const float* b1 = (const float*)d_in[5];
    const float* W2 = (const float*)d_in[6];
    const float* b2 = (const float*)d_in[7];
    float* out = (float*)d_out;
    unsigned short* wt = (unsigned short*)d_ws;   // 87040 bytes used

    hipMemsetAsync(out, 0, (size_t)N_NODES * DIM_OUT * sizeof(float), stream);

    const int wn = 320 * PAD;                     // 43520 bf16 elements
    prep_weights<<<(wn + 255) / 256, 256, 0, stream>>>(W0, W1, W2, wt);

    edge_mlp_mfma<<<N_EDGES / 128, 256, 0, stream>>>(x, ei, wt, b0, b1, b2, out);
}

// Round 5
// 294.806 us; speedup vs baseline: 2.6209x; 2.6209x over previous
//
#include <hip/hip_runtime.h>
#include <math.h>

#define N_NODES 50000
#define N_EDGES 800000
#define DIM_IN 64
#define DIM_HID 128
#define DIM_OUT 64
#define PAD 136   // bf16 per weight row: 272B, 16B-aligned

typedef __attribute__((ext_vector_type(8))) short short8;   // 8 bf16 (4 VGPRs)
typedef __attribute__((ext_vector_type(4))) float f32x4;    // MFMA accumulator

union U8 { uint4 u; short8 s; };

// RTNE float->bf16 (inputs finite)
__device__ __forceinline__ unsigned short f2bf(float f) {
    unsigned u = __float_as_uint(f);
    return (unsigned short)((u + 0x7fffu + ((u >> 16) & 1u)) >> 16);
}

__device__ __forceinline__ unsigned cvt_pk_bf16(float a, float b) {
#if __has_builtin(__builtin_amdgcn_cvt_pk_bf16_f32)
    auto pk = __builtin_amdgcn_cvt_pk_bf16_f32(a, b);   // lo=a, hi=b
    unsigned d; __builtin_memcpy(&d, &pk, 4);
    return d;
#else
    return (unsigned)f2bf(a) | ((unsigned)f2bf(b) << 16);
#endif
}

__device__ __forceinline__ float exp2_fast(float a) {
#if __has_builtin(__builtin_amdgcn_exp2f)
    return __builtin_amdgcn_exp2f(a);
#else
    return __expf(a * 0.69314718f);
#endif
}

// softplus(x) = max(x,0) + log1p(exp(-|x|)); log1p(z) ~ z*(1 + z*(-0.5 + z*(A + z*B)))
// cubic fit on z in (0,1], max abs err ~1.5e-3 (below bf16 quantization of H)
__device__ __forceinline__ unsigned sp2(float x0, float x1) {
    const float L2E = 1.44269504f;
    float z0 = exp2_fast(-fabsf(x0) * L2E);
    float z1 = exp2_fast(-fabsf(x1) * L2E);
    float p0 = fmaf(fmaf(fmaf(-0.1011458f, z0, 0.2942925f), z0, -0.5f), z0, 1.0f) * z0;
    float p1 = fmaf(fmaf(fmaf(-0.1011458f, z1, 0.2942925f), z1, -0.5f), z1, 1.0f) * z1;
    return cvt_pk_bf16(fmaxf(x0, 0.0f) + p0, fmaxf(x1, 0.0f) + p1);
}

// Weights -> bf16 W^T [n][PAD] (k-contiguous). Layers 1,2 get the K-permutation
// pi(s) matching the MFMA C-layout->frag register renaming (see kernel). pi is
// the same for B-frag (layer 1) and A-frag (layer 2) use, since both frags share
// the slot structure s = kk*32 + q*8 + j.
__global__ void prep_weights(const float* __restrict__ W0,
                             const float* __restrict__ W1,
                             const float* __restrict__ W2,
                             unsigned short* __restrict__ wt) {
    int i = blockIdx.x * blockDim.x + threadIdx.x;
    if (i >= 320 * PAD) return;
    int row = i / PAD, s = i - row * PAD;
    float v = 0.f;
    if (s < 128) {
        int f = ((s >> 5) << 5) | (((s & 7) >> 2) << 4) | (((s >> 3) & 3) << 2) | (s & 3);
        if (row < 128)      v = W0[s * DIM_HID + row];          // layer 0: natural k
        else if (row < 256) v = W1[f * DIM_HID + (row - 128)];  // layer 1: permuted k
        else                v = W2[f * DIM_OUT + (row - 256)];  // layer 2: permuted k
    }
    wt[i] = f2bf(v);
}

// Layers 0,1 flipped: H^T = softplus(W^T H^T + b) via mfma(A=weight, B=activation).
// C-layout: col=l16=edge, row=q*4+r=feature -> lane keeps its own edges' features;
// inter-layer transform = softplus + cvt_pk + register renaming (pi in weights).
// Layer 2 un-flipped: O = H W2 + b2 via mfma(A=activation(hfr), B=weight).
// C-layout: row=q*4+r=edge, col=l16=feature -> node uniform per quad, scatter
// fills full 64B sectors (coalesced atomics). No LDS, no barriers, no shuffles.
__global__ __launch_bounds__(256, 4)
void edge_mlp_mfma(const float* __restrict__ x,
                   const int* __restrict__ eidx,
                   const unsigned short* __restrict__ wt,
                   const float* __restrict__ b0,
                   const float* __restrict__ b1,
                   const float* __restrict__ b2,
                   float* __restrict__ out) {
    const int lane = threadIdx.x & 63;
    const int w    = threadIdx.x >> 6;
    const int l16  = lane & 15;
    const int q    = lane >> 4;
    const int e0w  = blockIdx.x * 128 + w * 32;   // this wave's 32 edges

    const unsigned short* Wt0 = wt;
    const unsigned short* Wt1 = wt + 128 * PAD;
    const unsigned short* Wt2 = wt + 256 * PAD;

    int nodeR[2], nodeC[2];
#pragma unroll
    for (int m = 0; m < 2; ++m) {
        nodeR[m] = eidx[e0w + m * 16 + l16];
        nodeC[m] = eidx[N_EDGES + e0w + m * 16 + l16];
    }

    // layer-0 B-frags straight from x: B(k=kk*32+q*8+j, edge=m*16+l16)
    short8 hfr[2][4];
#pragma unroll
    for (int m = 0; m < 2; ++m)
#pragma unroll
        for (int kk = 0; kk < 4; ++kk) {
            int node = (kk >= 2) ? nodeC[m] : nodeR[m];
            const float* p = x + (size_t)node * DIM_IN + (kk & 1) * 32 + q * 8;
            float4 v0 = *(const float4*)p;
            float4 v1 = *(const float4*)(p + 4);
            U8 t;
            t.u.x = cvt_pk_bf16(v0.x, v0.y);
            t.u.y = cvt_pk_bf16(v0.z, v0.w);
            t.u.z = cvt_pk_bf16(v1.x, v1.y);
            t.u.w = cvt_pk_bf16(v1.z, v1.w);
            hfr[m][kk] = t.s;
        }

    // ---- layers 0,1: H^T = softplus(W^T H^T + b) ----
#pragma unroll
    for (int L = 0; L < 2; ++L) {
        const unsigned short* W = L ? Wt1 : Wt0;
        const float* bias = L ? b1 : b0;
        unsigned d[2][8][2];
#pragma unroll
        for (int ti = 0; ti < 8; ++ti) {
            f32x4 bb = *(const f32x4*)(bias + ti * 16 + q * 4);  // bias on row dim
            f32x4 a0 = bb, a1 = bb;
            const unsigned short* Wp = W + (ti * 16 + l16) * PAD + q * 8;
            short8 wf[4];
#pragma unroll
            for (int kk = 0; kk < 4; ++kk)
                wf[kk] = *(const short8*)(Wp + kk * 32);
#pragma unroll
            for (int kk = 0; kk < 4; ++kk) {
                a0 = __builtin_amdgcn_mfma_f32_16x16x32_bf16(wf[kk], hfr[0][kk], a0, 0, 0, 0);
                a1 = __builtin_amdgcn_mfma_f32_16x16x32_bf16(wf[kk], hfr[1][kk], a1, 0, 0, 0);
            }
            // per-ti epilogue keeps acc liveness at 8 VGPRs
            d[0][ti][0] = sp2(a0[0], a0[1]);
            d[0][ti][1] = sp2(a0[2], a0[3]);
            d[1][ti][0] = sp2(a1[0], a1[1]);
            d[1][ti][1] = sp2(a1[2], a1[3]);
        }
        // next-layer frags: pure register renaming (weights carry pi)
#pragma unroll
        for (int m = 0; m < 2; ++m)
#pragma unroll
            for (int kk = 0; kk < 4; ++kk) {
                U8 t;
                t.u.x = d[m][2 * kk][0];
                t.u.y = d[m][2 * kk][1];
                t.u.z = d[m][2 * kk + 1][0];
                t.u.w = d[m][2 * kk + 1][1];
                hfr[m][kk] = t.s;
            }
    }

    // ---- layer 2 (un-flipped): O = H W2 + b2; C row=edge, col=feature ----
    int nodeO[2][4];
#pragma unroll
    for (int m = 0; m < 2; ++m)
#pragma unroll
        for (int r = 0; r < 4; ++r)
            nodeO[m][r] = eidx[e0w + m * 16 + q * 4 + r];   // L1-hot reload

#pragma unroll
    for (int ti = 0; ti < 4; ++ti) {
        float bv = b2[ti * 16 + l16];                        // bias on col dim
        f32x4 a0 = (f32x4){bv, bv, bv, bv};
        f32x4 a1 = a0;
        const unsigned short* Wp = Wt2 + (ti * 16 + l16) * PAD + q * 8;
        short8 wf[4];
#pragma unroll
        for (int kk = 0; kk < 4; ++kk)
            wf[kk] = *(const short8*)(Wp + kk * 32);
#pragma unroll
        for (int kk = 0; kk < 4; ++kk) {
            a0 = __builtin_amdgcn_mfma_f32_16x16x32_bf16(hfr[0][kk], wf[kk], a0, 0, 0, 0);
            a1 = __builtin_amdgcn_mfma_f32_16x16x32_bf16(hfr[1][kk], wf[kk], a1, 0, 0, 0);
        }
#pragma unroll
        for (int r = 0; r < 4; ++r) {
            atomicAdd(out + (size_t)nodeO[0][r] * DIM_OUT + ti * 16 + l16, a0[r]);
            atomicAdd(out + (size_t)nodeO[1][r] * DIM_OUT + ti * 16 + l16, a1[r]);
        }
    }
}

extern "C" void kernel_launch(void* const* d_in, const int* in_sizes, int n_in,
                              void* d_out, int out_size, void* d_ws, size_t ws_size,
                              hipStream_t stream) {
    const float* x  = (const float*)d_in[0];
    const int*   ei = (const int*)d_in[1];
    const float* W0 = (const float*)d_in[2];
    const float* b0 = (const float*)d_in[3];
    const float* W1 = (const float*)d_in[4];
    const float* b1 = (const float*)d_in[5];
    const float* W2 = (const float*)d_in[6];
    const float* b2 = (const float*)d_in[7];
    float* out = (float*)d_out;
    unsigned short* wt = (unsigned short*)d_ws;   // 87040 bytes used

    hipMemsetAsync(out, 0, (size_t)N_NODES * DIM_OUT * sizeof(float), stream);

    const int wn = 320 * PAD;                     // 43520 bf16 elements
    prep_weights<<<(wn + 255) / 256, 256, 0, stream>>>(W0, W1, W2, wt);

    edge_mlp_mfma<<<N_EDGES / 128, 256, 0, stream>>>(x, ei, wt, b0, b1, b2, out);
}